// Round 1
// baseline (17897.223 us; speedup 1.0000x reference)
//
#include <hip/hip_runtime.h>
#include <hip/hip_bf16.h>
#include <math.h>

// Problem constants: B=2, S=2048, E=1024, H=16, D=64, buckets used: 0..127 (causal => rel>=0)

// ---------------- SGEMM 128x128 tile, K-step 16, fp32 ----------------
// MODE 0: C[m*1024+n] plain row-major   MODE 1: scatter to [B,H,S,D] head layout
template<int MODE>
__global__ void sgemm128(const float* __restrict__ A, const float* __restrict__ W,
                         float* __restrict__ C)
{
    __shared__ float As[16*128];   // As[k][m]
    __shared__ float Bs[16*128];   // Bs[k][n]
    const int tid = threadIdx.x;
    const int tx = tid & 15, ty = tid >> 4;
    const int bx = blockIdx.x, by = blockIdx.y;
    const int arow = tid >> 1;          // 0..127
    const int acol = (tid & 1) * 8;     // 0 or 8
    const int brow = tid >> 4;          // 0..15
    const int bcol = (tid & 15) * 8;    // 0..120

    float acc[8][8];
#pragma unroll
    for (int i = 0; i < 8; ++i)
#pragma unroll
        for (int j = 0; j < 8; ++j) acc[i][j] = 0.f;

    const float* ap = A + (size_t)(by*128 + arow)*1024 + acol;
    const float* bp = W + (size_t)brow*1024 + bx*128 + bcol;

    for (int k0 = 0; k0 < 1024; k0 += 16) {
        float4 a0 = *(const float4*)(ap + k0);
        float4 a1 = *(const float4*)(ap + k0 + 4);
        float4 b0 = *(const float4*)(bp + (size_t)k0*1024);
        float4 b1 = *(const float4*)(bp + (size_t)k0*1024 + 4);
        As[(acol+0)*128 + arow] = a0.x;
        As[(acol+1)*128 + arow] = a0.y;
        As[(acol+2)*128 + arow] = a0.z;
        As[(acol+3)*128 + arow] = a0.w;
        As[(acol+4)*128 + arow] = a1.x;
        As[(acol+5)*128 + arow] = a1.y;
        As[(acol+6)*128 + arow] = a1.z;
        As[(acol+7)*128 + arow] = a1.w;
        *(float4*)&Bs[brow*128 + bcol]     = b0;
        *(float4*)&Bs[brow*128 + bcol + 4] = b1;
        __syncthreads();
#pragma unroll
        for (int kk = 0; kk < 16; ++kk) {
            float a[8], b[8];
            *(float4*)&a[0] = *(const float4*)&As[kk*128 + ty*8];
            *(float4*)&a[4] = *(const float4*)&As[kk*128 + ty*8 + 4];
            *(float4*)&b[0] = *(const float4*)&Bs[kk*128 + tx*8];
            *(float4*)&b[4] = *(const float4*)&Bs[kk*128 + tx*8 + 4];
#pragma unroll
            for (int i = 0; i < 8; ++i)
#pragma unroll
                for (int j = 0; j < 8; ++j)
                    acc[i][j] = fmaf(a[i], b[j], acc[i][j]);
        }
        __syncthreads();
    }
    const int n0 = bx*128 + tx*8;
#pragma unroll
    for (int i = 0; i < 8; ++i) {
        const int m = by*128 + ty*8 + i;
        float4 st0 = make_float4(acc[i][0], acc[i][1], acc[i][2], acc[i][3]);
        float4 st1 = make_float4(acc[i][4], acc[i][5], acc[i][6], acc[i][7]);
        if (MODE == 0) {
            float* o = C + (size_t)m*1024 + n0;
            *(float4*)o     = st0;
            *(float4*)(o+4) = st1;
        } else {
            const int bb = m >> 11, ss = m & 2047;
            const int hh = n0 >> 6, dd = n0 & 63;   // 8-col chunk never crosses a head
            float* o = C + ((((size_t)bb*16 + hh)*2048 + ss)*64 + dd);
            *(float4*)o     = st0;
            *(float4*)(o+4) = st1;
        }
    }
}

// ---------------- RoPE (in place on q and k, [B,H,S,D]) ----------------
// out[d] = t[d]*cos(s*invf[d>>1]) + rot[d]*sin(...), rot[d] = -t[d+32] (d<32) / t[d-32] (d>=32)
__global__ void rope_kernel(float* __restrict__ q, float* __restrict__ k)
{
    const int t = blockIdx.x * 256 + threadIdx.x;    // 0 .. 2^22-1
    const int ten = t >> 21;                         // 0:q 1:k
    const int r = t & ((1 << 21) - 1);
    const int dd = r & 31;                           // low half element
    const int s  = (r >> 5) & 2047;
    const int bh = r >> 16;                          // 0..31
    float* p = ten ? k : q;
    const size_t base = ((size_t)bh*2048 + s)*64;
    const float x0 = p[base + dd];
    const float x1 = p[base + dd + 32];
    const float f0 = (float)(dd >> 1);
    const float CC = 0.41524101186092029f;           // log2(10000)/32
    const float if0 = exp2f(-f0 * CC);
    const float if1 = exp2f(-(f0 + 16.f) * CC);
    const float a0 = (float)s * if0;
    const float a1 = (float)s * if1;
    p[base + dd]      = x0 * cosf(a0) - x1 * sinf(a0);
    p[base + dd + 32] = x1 * cosf(a1) + x0 * sinf(a1);
}

// ---------------- q_rel = q . rel_emb  ->  [B*H, S, 128] (only buckets 0..127 reachable) ----------------
__global__ void qrel_kernel(const float* __restrict__ q, const float* __restrict__ rel_emb,
                            float* __restrict__ qrel)
{
    __shared__ float qs[64*65];      // padded rows: conflict-free per-lane row reads
    __shared__ float rls[128*64];    // uniform (broadcast) reads
    const int tid = threadIdx.x;
    const int s0 = blockIdx.x * 64;
    const int bh = blockIdx.y;
    const int h  = bh & 15;

    for (int idx = tid; idx < 64*16; idx += 256) {
        int r = idx >> 4, c4 = (idx & 15) << 2;
        float4 vv = *(const float4*)(q + ((size_t)bh*2048 + s0 + r)*64 + c4);
        qs[r*65 + c4 + 0] = vv.x;
        qs[r*65 + c4 + 1] = vv.y;
        qs[r*65 + c4 + 2] = vv.z;
        qs[r*65 + c4 + 3] = vv.w;
    }
    for (int idx = tid; idx < 128*16; idx += 256) {
        int n = idx >> 4, c4 = (idx & 15) << 2;
        *(float4*)&rls[n*64 + c4] = *(const float4*)(rel_emb + ((size_t)n*16 + h)*64 + c4);
    }
    __syncthreads();

    const int r  = tid & 63;
    const int nb = tid >> 6;         // uniform per wave -> rls reads broadcast
    float* orow = qrel + ((size_t)bh*2048 + s0 + r)*128;
#pragma unroll 1
    for (int kq = 0; kq < 8; ++kq) {
        const int n0 = nb*4 + kq*16;
        float a0 = 0.f, a1 = 0.f, a2 = 0.f, a3 = 0.f;
#pragma unroll
        for (int d = 0; d < 64; ++d) {
            const float qv = qs[r*65 + d];
            a0 = fmaf(qv, rls[(n0+0)*64 + d], a0);
            a1 = fmaf(qv, rls[(n0+1)*64 + d], a1);
            a2 = fmaf(qv, rls[(n0+2)*64 + d], a2);
            a3 = fmaf(qv, rls[(n0+3)*64 + d], a3);
        }
        float4 st = make_float4(a0, a1, a2, a3);
        *(float4*)&orow[n0] = st;
    }
}

// ---------------- causal flash attention with rel-pos bias gather ----------------
// 1 wave / block, 64 q-rows (lane-per-row), K/V tiles of 32 rows in LDS.
__global__ void flash_kernel(const float* __restrict__ q, const float* __restrict__ k,
                             const float* __restrict__ v, const float* __restrict__ qrel,
                             float* __restrict__ ctx)
{
    __shared__ float kls[32][68];
    __shared__ float vls[32][68];
    const int l  = threadIdx.x;
    const int i0 = blockIdx.x * 64;
    const int bh = blockIdx.y;
    const int i  = i0 + l;
    const float* qrow    = q    + ((size_t)bh*2048 + i)*64;
    const float* qrelrow = qrel + ((size_t)bh*2048 + i)*128;

    float qreg[64];
#pragma unroll
    for (int c = 0; c < 16; ++c) {
        float4 vv = ((const float4*)qrow)[c];
        qreg[4*c+0] = vv.x; qreg[4*c+1] = vv.y; qreg[4*c+2] = vv.z; qreg[4*c+3] = vv.w;
    }
    float acc[64];
#pragma unroll
    for (int d = 0; d < 64; ++d) acc[d] = 0.f;
    float mrun = -INFINITY, lsum = 0.f;

    const int ntiles = (i0 >> 5) + 2;    // covers j <= i0+63
    const int sl = l & 31;
    const float* stage_src = ((l < 32) ? k : v) + ((size_t)bh*2048 + sl)*64;
    float* stage_dst = (l < 32) ? &kls[sl][0] : &vls[sl][0];

    for (int t = 0; t < ntiles; ++t) {
        const int j0 = t * 32;
        const float4* src4 = (const float4*)(stage_src + (size_t)j0*64);
        float4* dst4 = (float4*)stage_dst;
#pragma unroll
        for (int c = 0; c < 16; ++c) dst4[c] = src4[c];
        __syncthreads();

        float sv[32];
        float tmax = -INFINITY;
#pragma unroll
        for (int kk = 0; kk < 32; ++kk) {
            const float4* kr = (const float4*)&kls[kk][0];
            float dot = 0.f;
#pragma unroll
            for (int c = 0; c < 16; ++c) {
                float4 kv = kr[c];
                dot = fmaf(qreg[4*c+0], kv.x, dot);
                dot = fmaf(qreg[4*c+1], kv.y, dot);
                dot = fmaf(qreg[4*c+2], kv.z, dot);
                dot = fmaf(qreg[4*c+3], kv.w, dot);
            }
            const int rel = i - (j0 + kk);
            int bkt;
            if (rel < 64) {
                bkt = (rel < 0) ? 0 : rel;
            } else {
                bkt = 64 + (int)(log2f((float)rel * 0.015625f) * 8.0f);
                bkt = bkt > 127 ? 127 : bkt;
            }
            const float bias  = qrelrow[bkt];
            const float sfull = (dot + bias) * 0.125f;
            sv[kk] = (rel >= 0) ? sfull : -1e30f;
            tmax = fmaxf(tmax, sv[kk]);
        }
        const float newm = fmaxf(mrun, tmax);
        const float corr = __expf(mrun - newm);   // exp(-inf)=0 on first tile
        lsum *= corr;
#pragma unroll
        for (int d = 0; d < 64; ++d) acc[d] *= corr;
#pragma unroll
        for (int kk = 0; kk < 32; ++kk) {
            const float p = __expf(sv[kk] - newm);  // masked -> exp(~-1e30) = 0
            lsum += p;
            const float4* vr = (const float4*)&vls[kk][0];
#pragma unroll
            for (int c = 0; c < 16; ++c) {
                float4 vvv = vr[c];
                acc[4*c+0] = fmaf(p, vvv.x, acc[4*c+0]);
                acc[4*c+1] = fmaf(p, vvv.y, acc[4*c+1]);
                acc[4*c+2] = fmaf(p, vvv.z, acc[4*c+2]);
                acc[4*c+3] = fmaf(p, vvv.w, acc[4*c+3]);
            }
        }
        mrun = newm;
        __syncthreads();
    }

    const float inv = 1.0f / lsum;
    float* orow = ctx + ((((size_t)(bh >> 4))*2048 + i)*16 + (bh & 15))*64;  // [B,S,H,D]
#pragma unroll
    for (int c = 0; c < 16; ++c) {
        float4 st = make_float4(acc[4*c+0]*inv, acc[4*c+1]*inv, acc[4*c+2]*inv, acc[4*c+3]*inv);
        ((float4*)orow)[c] = st;
    }
}

extern "C" void kernel_launch(void* const* d_in, const int* in_sizes, int n_in,
                              void* d_out, int out_size, void* d_ws, size_t ws_size,
                              hipStream_t stream)
{
    const float* x   = (const float*)d_in[0];
    const float* Wq  = (const float*)d_in[1];
    const float* Wk  = (const float*)d_in[2];
    const float* Wv  = (const float*)d_in[3];
    const float* Wo  = (const float*)d_in[4];
    const float* rel = (const float*)d_in[5];

    float* ws   = (float*)d_ws;
    float* q    = ws;                    // [B,H,S,D]  4,194,304 f
    float* kbuf = ws + 4194304;          // [B,H,S,D]
    float* vbuf = ws + 8388608;          // [B,H,S,D]
    float* qrel = ws + 12582912;         // [B*H,S,128] 8,388,608 f
    float* ctx  = ws + 20971520;         // [B,S,H,D]  4,194,304 f  (total 96 MB)

    dim3 gemm_grid(8, 32);
    sgemm128<1><<<gemm_grid, 256, 0, stream>>>(x, Wq, q);
    sgemm128<1><<<gemm_grid, 256, 0, stream>>>(x, Wk, kbuf);
    sgemm128<1><<<gemm_grid, 256, 0, stream>>>(x, Wv, vbuf);
    rope_kernel<<<16384, 256, 0, stream>>>(q, kbuf);
    qrel_kernel<<<dim3(32, 32), 256, 0, stream>>>(q, rel, qrel);
    flash_kernel<<<dim3(32, 32), 64, 0, stream>>>(q, kbuf, vbuf, qrel, ctx);
    sgemm128<0><<<gemm_grid, 256, 0, stream>>>(ctx, Wo, (float*)d_out);
}

// Round 2
// 2995.314 us; speedup vs baseline: 5.9751x; 5.9751x over previous
//
#include <hip/hip_runtime.h>
#include <hip/hip_bf16.h>
#include <math.h>

// Problem constants: B=2, S=2048, E=1024, H=16, D=64, buckets used: 0..127 (causal => rel>=0)

// ---------------- SGEMM 128x128 tile, K-step 16, fp32 ----------------
// MODE 0: C[m*1024+n] plain row-major   MODE 1: scatter to [B,H,S,D] head layout
template<int MODE>
__global__ void sgemm128(const float* __restrict__ A, const float* __restrict__ W,
                         float* __restrict__ C)
{
    __shared__ float As[16*128];   // As[k][m]
    __shared__ float Bs[16*128];   // Bs[k][n]
    const int tid = threadIdx.x;
    const int tx = tid & 15, ty = tid >> 4;
    const int bx = blockIdx.x, by = blockIdx.y;
    const int arow = tid >> 1;          // 0..127
    const int acol = (tid & 1) * 8;     // 0 or 8
    const int brow = tid >> 4;          // 0..15
    const int bcol = (tid & 15) * 8;    // 0..120

    float acc[8][8];
#pragma unroll
    for (int i = 0; i < 8; ++i)
#pragma unroll
        for (int j = 0; j < 8; ++j) acc[i][j] = 0.f;

    const float* ap = A + (size_t)(by*128 + arow)*1024 + acol;
    const float* bp = W + (size_t)brow*1024 + bx*128 + bcol;

    for (int k0 = 0; k0 < 1024; k0 += 16) {
        float4 a0 = *(const float4*)(ap + k0);
        float4 a1 = *(const float4*)(ap + k0 + 4);
        float4 b0 = *(const float4*)(bp + (size_t)k0*1024);
        float4 b1 = *(const float4*)(bp + (size_t)k0*1024 + 4);
        As[(acol+0)*128 + arow] = a0.x;
        As[(acol+1)*128 + arow] = a0.y;
        As[(acol+2)*128 + arow] = a0.z;
        As[(acol+3)*128 + arow] = a0.w;
        As[(acol+4)*128 + arow] = a1.x;
        As[(acol+5)*128 + arow] = a1.y;
        As[(acol+6)*128 + arow] = a1.z;
        As[(acol+7)*128 + arow] = a1.w;
        *(float4*)&Bs[brow*128 + bcol]     = b0;
        *(float4*)&Bs[brow*128 + bcol + 4] = b1;
        __syncthreads();
#pragma unroll
        for (int kk = 0; kk < 16; ++kk) {
            float a[8], b[8];
            *(float4*)&a[0] = *(const float4*)&As[kk*128 + ty*8];
            *(float4*)&a[4] = *(const float4*)&As[kk*128 + ty*8 + 4];
            *(float4*)&b[0] = *(const float4*)&Bs[kk*128 + tx*8];
            *(float4*)&b[4] = *(const float4*)&Bs[kk*128 + tx*8 + 4];
#pragma unroll
            for (int i = 0; i < 8; ++i)
#pragma unroll
                for (int j = 0; j < 8; ++j)
                    acc[i][j] = fmaf(a[i], b[j], acc[i][j]);
        }
        __syncthreads();
    }
    const int n0 = bx*128 + tx*8;
#pragma unroll
    for (int i = 0; i < 8; ++i) {
        const int m = by*128 + ty*8 + i;
        float4 st0 = make_float4(acc[i][0], acc[i][1], acc[i][2], acc[i][3]);
        float4 st1 = make_float4(acc[i][4], acc[i][5], acc[i][6], acc[i][7]);
        if (MODE == 0) {
            float* o = C + (size_t)m*1024 + n0;
            *(float4*)o     = st0;
            *(float4*)(o+4) = st1;
        } else {
            const int bb = m >> 11, ss = m & 2047;
            const int hh = n0 >> 6, dd = n0 & 63;   // 8-col chunk never crosses a head
            float* o = C + ((((size_t)bb*16 + hh)*2048 + ss)*64 + dd);
            *(float4*)o     = st0;
            *(float4*)(o+4) = st1;
        }
    }
}

// ---------------- RoPE (in place on q and k, [B,H,S,D]) ----------------
__global__ void rope_kernel(float* __restrict__ q, float* __restrict__ k)
{
    const int t = blockIdx.x * 256 + threadIdx.x;    // 0 .. 2^22-1
    const int ten = t >> 21;                         // 0:q 1:k
    const int r = t & ((1 << 21) - 1);
    const int dd = r & 31;                           // low half element
    const int s  = (r >> 5) & 2047;
    const int bh = r >> 16;                          // 0..31
    float* p = ten ? k : q;
    const size_t base = ((size_t)bh*2048 + s)*64;
    const float x0 = p[base + dd];
    const float x1 = p[base + dd + 32];
    const float f0 = (float)(dd >> 1);
    const float CC = 0.41524101186092029f;           // log2(10000)/32
    const float if0 = exp2f(-f0 * CC);
    const float if1 = exp2f(-(f0 + 16.f) * CC);
    const float a0 = (float)s * if0;
    const float a1 = (float)s * if1;
    p[base + dd]      = x0 * cosf(a0) - x1 * sinf(a0);
    p[base + dd + 32] = x1 * cosf(a1) + x0 * sinf(a1);
}

// ---------------- q_rel = q . rel_emb  ->  [B*H, S, 128] ----------------
__global__ void qrel_kernel(const float* __restrict__ q, const float* __restrict__ rel_emb,
                            float* __restrict__ qrel)
{
    __shared__ float qs[64*65];
    __shared__ float rls[128*64];
    const int tid = threadIdx.x;
    const int s0 = blockIdx.x * 64;
    const int bh = blockIdx.y;
    const int h  = bh & 15;

    for (int idx = tid; idx < 64*16; idx += 256) {
        int r = idx >> 4, c4 = (idx & 15) << 2;
        float4 vv = *(const float4*)(q + ((size_t)bh*2048 + s0 + r)*64 + c4);
        qs[r*65 + c4 + 0] = vv.x;
        qs[r*65 + c4 + 1] = vv.y;
        qs[r*65 + c4 + 2] = vv.z;
        qs[r*65 + c4 + 3] = vv.w;
    }
    for (int idx = tid; idx < 128*16; idx += 256) {
        int n = idx >> 4, c4 = (idx & 15) << 2;
        *(float4*)&rls[n*64 + c4] = *(const float4*)(rel_emb + ((size_t)n*16 + h)*64 + c4);
    }
    __syncthreads();

    const int r  = tid & 63;
    const int nb = tid >> 6;
    float* orow = qrel + ((size_t)bh*2048 + s0 + r)*128;
#pragma unroll 1
    for (int kq = 0; kq < 8; ++kq) {
        const int n0 = nb*4 + kq*16;
        float a0 = 0.f, a1 = 0.f, a2 = 0.f, a3 = 0.f;
#pragma unroll
        for (int d = 0; d < 64; ++d) {
            const float qv = qs[r*65 + d];
            a0 = fmaf(qv, rls[(n0+0)*64 + d], a0);
            a1 = fmaf(qv, rls[(n0+1)*64 + d], a1);
            a2 = fmaf(qv, rls[(n0+2)*64 + d], a2);
            a3 = fmaf(qv, rls[(n0+3)*64 + d], a3);
        }
        float4 st = make_float4(a0, a1, a2, a3);
        *(float4*)&orow[n0] = st;
    }
}

// ---------------- causal flash attention, 256 thr / 4 waves / 64 q-rows ----------------
// 4 lanes per q-row (16 dims each). K/V 32-row tiles + per-row qrel bias rows in LDS.
__global__ __launch_bounds__(256) void flash_kernel(
    const float* __restrict__ q, const float* __restrict__ k,
    const float* __restrict__ v, const float* __restrict__ qrel,
    float* __restrict__ ctx)
{
    __shared__ float kls[32][68];
    __shared__ float vls[32][68];
    __shared__ float qrels[64*132];    // pad 132: float4-aligned rows, conflict-free gathers
    const int tid = threadIdx.x;
    const int i0 = blockIdx.x * 64;
    const int bh = blockIdx.y;
    const int wave = tid >> 6;
    const int lane = tid & 63;
    const int row  = wave*16 + (lane >> 2);   // local q-row 0..63
    const int c    = lane & 3;                // dim chunk: c*16 .. c*16+15
    const int i    = i0 + row;

    // stage qrel rows for this block's 64 q-rows
    for (int idx = tid; idx < 64*32; idx += 256) {
        const int r  = idx >> 5;
        const int c4 = (idx & 31) << 2;
        float4 vv = *(const float4*)(qrel + ((size_t)bh*2048 + i0 + r)*128 + c4);
        *(float4*)&qrels[r*132 + c4] = vv;
    }

    // q fragment: 16 dims
    float qreg[16];
    {
        const float* qrow = q + ((size_t)bh*2048 + i)*64 + c*16;
#pragma unroll
        for (int cc = 0; cc < 4; ++cc) {
            float4 vv = ((const float4*)qrow)[cc];
            qreg[4*cc+0] = vv.x; qreg[4*cc+1] = vv.y;
            qreg[4*cc+2] = vv.z; qreg[4*cc+3] = vv.w;
        }
    }
    float acc[16];
#pragma unroll
    for (int d = 0; d < 16; ++d) acc[d] = 0.f;
    float mrun = -INFINITY, lsum = 0.f;

    // staging: tids 0..127 -> K, 128..255 -> V ; each thread 16 consecutive floats
    const int srow = (tid & 127) >> 2;
    const int scol = (tid & 3) * 16;
    const float* ssrc = ((tid < 128) ? k : v) + ((size_t)bh*2048 + srow)*64 + scol;
    float* sdst = (tid < 128) ? &kls[srow][scol] : &vls[srow][scol];

    const int ntiles = (i0 >> 5) + 2;
    for (int t = 0; t < ntiles; ++t) {
        const int j0 = t * 32;
        const float4* src4 = (const float4*)(ssrc + (size_t)j0*64);
        float4 ld0 = src4[0], ld1 = src4[1], ld2 = src4[2], ld3 = src4[3];
        __syncthreads();   // previous tile fully consumed (also covers qrels staging at t=0)
        float4* dst4 = (float4*)sdst;
        dst4[0] = ld0; dst4[1] = ld1; dst4[2] = ld2; dst4[3] = ld3;
        __syncthreads();

        // partial dots over this lane's 16 dims
        float sv[32];
#pragma unroll
        for (int kk = 0; kk < 32; ++kk) {
            const float4* kr = (const float4*)&kls[kk][c*16];
            float dot = 0.f;
#pragma unroll
            for (int cc = 0; cc < 4; ++cc) {
                float4 kv = kr[cc];
                dot = fmaf(qreg[4*cc+0], kv.x, dot);
                dot = fmaf(qreg[4*cc+1], kv.y, dot);
                dot = fmaf(qreg[4*cc+2], kv.z, dot);
                dot = fmaf(qreg[4*cc+3], kv.w, dot);
            }
            sv[kk] = dot;
        }
        // reduce across the 4-lane group; add bias, scale, mask
        float tmax = -INFINITY;
#pragma unroll
        for (int kk = 0; kk < 32; ++kk) {
            float dot = sv[kk];
            dot += __shfl_xor(dot, 1);
            dot += __shfl_xor(dot, 2);
            const int rel = i - (j0 + kk);
            int bkt;
            if (rel < 64) {
                bkt = (rel < 0) ? 0 : rel;
            } else {
                bkt = 64 + (int)(log2f((float)rel * 0.015625f) * 8.0f);
                bkt = bkt > 127 ? 127 : bkt;
            }
            const float bias = qrels[row*132 + bkt];
            const float sfull = (dot + bias) * 0.125f;
            sv[kk] = (rel >= 0) ? sfull : -1e30f;
            tmax = fmaxf(tmax, sv[kk]);
        }
        const float newm = fmaxf(mrun, tmax);
        const float corr = __expf(mrun - newm);   // exp(-inf)=0 on first tile
        lsum *= corr;
#pragma unroll
        for (int d = 0; d < 16; ++d) acc[d] *= corr;
#pragma unroll
        for (int kk = 0; kk < 32; ++kk) {
            const float p = __expf(sv[kk] - newm);
            lsum += p;
            const float4* vr = (const float4*)&vls[kk][c*16];
#pragma unroll
            for (int cc = 0; cc < 4; ++cc) {
                float4 vv = vr[cc];
                acc[4*cc+0] = fmaf(p, vv.x, acc[4*cc+0]);
                acc[4*cc+1] = fmaf(p, vv.y, acc[4*cc+1]);
                acc[4*cc+2] = fmaf(p, vv.z, acc[4*cc+2]);
                acc[4*cc+3] = fmaf(p, vv.w, acc[4*cc+3]);
            }
        }
        mrun = newm;
    }

    const float inv = 1.0f / lsum;
    // ctx layout [B,S,H,D]
    float* orow = ctx + ((((size_t)(bh >> 4))*2048 + i)*16 + (bh & 15))*64 + c*16;
#pragma unroll
    for (int cc = 0; cc < 4; ++cc) {
        float4 st = make_float4(acc[4*cc+0]*inv, acc[4*cc+1]*inv,
                                acc[4*cc+2]*inv, acc[4*cc+3]*inv);
        ((float4*)orow)[cc] = st;
    }
}

extern "C" void kernel_launch(void* const* d_in, const int* in_sizes, int n_in,
                              void* d_out, int out_size, void* d_ws, size_t ws_size,
                              hipStream_t stream)
{
    const float* x   = (const float*)d_in[0];
    const float* Wq  = (const float*)d_in[1];
    const float* Wk  = (const float*)d_in[2];
    const float* Wv  = (const float*)d_in[3];
    const float* Wo  = (const float*)d_in[4];
    const float* rel = (const float*)d_in[5];

    float* ws   = (float*)d_ws;
    float* q    = ws;                    // [B,H,S,D]
    float* kbuf = ws + 4194304;          // [B,H,S,D]
    float* vbuf = ws + 8388608;          // [B,H,S,D]
    float* qrel = ws + 12582912;         // [B*H,S,128]
    float* ctx  = ws + 20971520;         // [B,S,H,D]

    dim3 gemm_grid(8, 32);
    sgemm128<1><<<gemm_grid, 256, 0, stream>>>(x, Wq, q);
    sgemm128<1><<<gemm_grid, 256, 0, stream>>>(x, Wk, kbuf);
    sgemm128<1><<<gemm_grid, 256, 0, stream>>>(x, Wv, vbuf);
    rope_kernel<<<16384, 256, 0, stream>>>(q, kbuf);
    qrel_kernel<<<dim3(32, 32), 256, 0, stream>>>(q, rel, qrel);
    flash_kernel<<<dim3(32, 32), 256, 0, stream>>>(q, kbuf, vbuf, qrel, ctx);
    sgemm128<0><<<gemm_grid, 256, 0, stream>>>(ctx, Wo, (float*)d_out);
}